// Round 8
// baseline (2411.258 us; speedup 1.0000x reference)
//
#include <hip/hip_runtime.h>
#include <math.h>

#define Bn 128
#define Tn 512
#define Dn 300
#define Hn 150
#define Gn 600   // 4*H
#define Ln 25

// ---------------- lengths from mask ----------------
__global__ __launch_bounds__(64) void k_len(const float* __restrict__ mask, int* __restrict__ lens) {
  int b = blockIdx.x, lane = threadIdx.x;
  float s = 0.f;
  for (int t = lane; t < Tn; t += 64) s += mask[b * Tn + t];
#pragma unroll
  for (int off = 32; off; off >>= 1) s += __shfl_xor(s, off);
  if (lane == 0) lens[b] = (int)(s + 0.5f);
}

// ---------------- input GEMM (chunked, double-buffered LDS + prefetch) ----------------
__global__ __launch_bounds__(256) void k_gemm_in(
    const float* __restrict__ X, const float* __restrict__ Wf, const float* __restrict__ Wb,
    const float* __restrict__ bihf, const float* __restrict__ bhhf,
    const float* __restrict__ bihb, const float* __restrict__ bhhb,
    const int* __restrict__ lens, float* __restrict__ XgfC, float* __restrict__ YbC,
    int lo_f, int lo_b, int tshift, int chSh) {
  const int tileR = blockIdx.x;
  const int b = tileR >> tshift;
  const int tloc = (tileR & ((1 << tshift) - 1)) << 6;
  const int dir = (blockIdx.y >= 10);
  const int t_lo = dir ? lo_b : lo_f;
  const int t0g = t_lo + tloc;
  if (t0g >= lens[b]) return;
  const int c0 = (blockIdx.y - dir * 10) << 6;

  __shared__ __align__(16) float As[2][16][64];
  __shared__ __align__(16) float Bs[2][16][64];
  const int tid = threadIdx.x;
  const int lr = tid >> 2;
  const int kg = (tid & 3) << 2;
  const int tx = tid & 15, ty = tid >> 4;
  float acc[4][4];
#pragma unroll
  for (int i = 0; i < 4; ++i)
#pragma unroll
    for (int j = 0; j < 4; ++j) acc[i][j] = 0.f;

  const float* Xrow = X + ((size_t)(b * Tn + t0g + lr)) * Dn;
  const int cgl = c0 + lr;
  const float* Wrow = (cgl < Gn) ? ((dir ? Wb : Wf) + (size_t)cgl * Dn) : nullptr;

  float4 av = make_float4(0.f, 0.f, 0.f, 0.f), bv = make_float4(0.f, 0.f, 0.f, 0.f);
  {
    int k = kg;
    av = *(const float4*)(Xrow + k);
    if (Wrow) bv = *(const float4*)(Wrow + k);
  }
  int buf = 0;
  for (int k0 = 0; k0 < Dn; k0 += 16) {
    As[buf][kg + 0][lr] = av.x; As[buf][kg + 1][lr] = av.y;
    As[buf][kg + 2][lr] = av.z; As[buf][kg + 3][lr] = av.w;
    Bs[buf][kg + 0][lr] = bv.x; Bs[buf][kg + 1][lr] = bv.y;
    Bs[buf][kg + 2][lr] = bv.z; Bs[buf][kg + 3][lr] = bv.w;
    __syncthreads();
    av = make_float4(0.f, 0.f, 0.f, 0.f); bv = make_float4(0.f, 0.f, 0.f, 0.f);
    int kn = k0 + 16 + kg;
    if (kn < Dn) {
      av = *(const float4*)(Xrow + kn);
      if (Wrow) bv = *(const float4*)(Wrow + kn);
    }
#pragma unroll
    for (int kk = 0; kk < 16; ++kk) {
      float4 a = *(const float4*)(&As[buf][kk][ty << 2]);
      float4 q = *(const float4*)(&Bs[buf][kk][tx << 2]);
      acc[0][0] = fmaf(a.x, q.x, acc[0][0]); acc[0][1] = fmaf(a.x, q.y, acc[0][1]);
      acc[0][2] = fmaf(a.x, q.z, acc[0][2]); acc[0][3] = fmaf(a.x, q.w, acc[0][3]);
      acc[1][0] = fmaf(a.y, q.x, acc[1][0]); acc[1][1] = fmaf(a.y, q.y, acc[1][1]);
      acc[1][2] = fmaf(a.y, q.z, acc[1][2]); acc[1][3] = fmaf(a.y, q.w, acc[1][3]);
      acc[2][0] = fmaf(a.z, q.x, acc[2][0]); acc[2][1] = fmaf(a.z, q.y, acc[2][1]);
      acc[2][2] = fmaf(a.z, q.z, acc[2][2]); acc[2][3] = fmaf(a.z, q.w, acc[2][3]);
      acc[3][0] = fmaf(a.w, q.x, acc[3][0]); acc[3][1] = fmaf(a.w, q.y, acc[3][1]);
      acc[3][2] = fmaf(a.w, q.z, acc[3][2]); acc[3][3] = fmaf(a.w, q.w, acc[3][3]);
    }
    buf ^= 1;
  }
  const int cg0 = c0 + (tx << 2);
  if (cg0 >= Gn) return;
  const float* bih = dir ? bihb : bihf;
  const float* bhh = dir ? bhhb : bhhf;
  float* out = dir ? YbC : XgfC;
  const size_t rowbase = ((size_t)b << chSh) + tloc;
#pragma unroll
  for (int i = 0; i < 4; ++i) {
    float4 r;
    r.x = acc[i][0] + bih[cg0 + 0] + bhh[cg0 + 0];
    r.y = acc[i][1] + bih[cg0 + 1] + bhh[cg0 + 1];
    r.z = acc[i][2] + bih[cg0 + 2] + bhh[cg0 + 2];
    r.w = acc[i][3] + bih[cg0 + 3] + bhh[cg0 + 3];
    *(float4*)(out + (rowbase + (ty << 2) + i) * Gn + cg0) = r;
  }
}

// ---------------- recurrent LSTM (chunked), one block per (batch, direction) ----------------
// 640 threads, thread=gate-row. Weights in 38 NAMED float4 (guaranteed VGPR residency,
// VGPR_Count must read ~170-200). h broadcast via wave-uniform v_readlane from 3 coalesced
// ds_read_b32 per wave (replaces 38x ds_read_b128 broadcast). FMA order ascending-k: bitwise
// identical to previous rounds.
#define RLF(HV, L) __int_as_float(__builtin_amdgcn_readlane(__float_as_int(HV), (L)))
#define F4(Q, HV, L0) do { \
  acc = fmaf(w##Q.x, RLF(HV, (L0) + 0), acc); \
  acc = fmaf(w##Q.y, RLF(HV, (L0) + 1), acc); \
  acc = fmaf(w##Q.z, RLF(HV, (L0) + 2), acc); \
  acc = fmaf(w##Q.w, RLF(HV, (L0) + 3), acc); } while (0)
#define WL(Q) do { float2 a_ = wr[2 * (Q)], b_ = wr[2 * (Q) + 1]; \
  w##Q = make_float4(a_.x, a_.y, b_.x, b_.y); } while (0)

__global__ __launch_bounds__(640) void k_lstm(
    const float* __restrict__ XgfC, const float* __restrict__ YbC,
    const float* __restrict__ Whf, const float* __restrict__ Whb,
    const int* __restrict__ lens, float* __restrict__ hf, float* __restrict__ hb,
    float* __restrict__ sHf, float* __restrict__ sCf,
    float* __restrict__ sHb, float* __restrict__ sCb,
    int lo_f, int lo_b, int chSh, int CH) {
  __shared__ __align__(16) float h_s[192];   // 150 live + pad to 192 so h2=h_s[128+lane] is in-bounds
  __shared__ __align__(16) float g_s[Gn];
  const int tid = threadIdx.x;
  const int lane = tid & 63;
  const int dir = blockIdx.x >> 7;
  const int b = blockIdx.x & 127;
  const int len = lens[b];
  const int lo = dir ? lo_b : lo_f;
  if (lo >= len) return;
  const int hi = min(lo + CH, len);
  const float* Xg = dir ? YbC : XgfC;
  const float* W = dir ? Whb : Whf;
  float* ho = dir ? hb : hf;
  float* sH = dir ? sHb : sHf;
  float* sC = dir ? sCb : sCf;
  const bool init = dir ? (hi == len) : (lo == 0);

  if (tid < 192) h_s[tid] = 0.f;
  float c = 0.f;
  if (!init && tid < Hn) { h_s[tid] = sH[b * Hn + tid]; c = sC[b * Hn + tid]; }

  const int col = tid;
  float4 w0, w1, w2, w3, w4, w5, w6, w7, w8, w9, w10, w11, w12, w13, w14, w15,
         w16, w17, w18, w19, w20, w21, w22, w23, w24, w25, w26, w27, w28, w29,
         w30, w31, w32, w33, w34, w35, w36, w37;
  if (col < Gn) {
    const float2* wr = (const float2*)(W + (size_t)col * Hn);   // col*600B: 8B aligned
    WL(0);  WL(1);  WL(2);  WL(3);  WL(4);  WL(5);  WL(6);  WL(7);
    WL(8);  WL(9);  WL(10); WL(11); WL(12); WL(13); WL(14); WL(15);
    WL(16); WL(17); WL(18); WL(19); WL(20); WL(21); WL(22); WL(23);
    WL(24); WL(25); WL(26); WL(27); WL(28); WL(29); WL(30); WL(31);
    WL(32); WL(33); WL(34); WL(35); WL(36);
    { float2 a_ = wr[74]; w37 = make_float4(a_.x, a_.y, 0.f, 0.f); }  // k=148,149; 150,151 pad=0
  }
  __syncthreads();

  const int nst = hi - lo;
  const size_t cb = ((size_t)b << chSh);
  const size_t bT = (size_t)b * Tn;
  float xcur = 0.f;
  if (col < Gn) xcur = Xg[(cb + (dir ? (hi - 1 - lo) : 0)) * Gn + col];
  for (int s = 0; s < nst; ++s) {
    const int rl = dir ? (hi - 1 - lo - s) : s;
    const int rg = lo + rl;
    // per-wave h slices (coalesced b32; pad lanes read zeros)
    float h0 = h_s[lane];
    float h1 = h_s[64 + lane];
    float h2 = h_s[128 + lane];
    float xn = 0.f;
    if (col < Gn && s + 1 < nst) {
      int rln = dir ? (rl - 1) : (rl + 1);
      xn = Xg[(cb + rln) * Gn + col];              // prefetch under this step's FMAs
    }
    if (col < Gn) {
      float acc = xcur;
      F4(0, h0, 0);   F4(1, h0, 4);   F4(2, h0, 8);   F4(3, h0, 12);
      F4(4, h0, 16);  F4(5, h0, 20);  F4(6, h0, 24);  F4(7, h0, 28);
      F4(8, h0, 32);  F4(9, h0, 36);  F4(10, h0, 40); F4(11, h0, 44);
      F4(12, h0, 48); F4(13, h0, 52); F4(14, h0, 56); F4(15, h0, 60);
      F4(16, h1, 0);  F4(17, h1, 4);  F4(18, h1, 8);  F4(19, h1, 12);
      F4(20, h1, 16); F4(21, h1, 20); F4(22, h1, 24); F4(23, h1, 28);
      F4(24, h1, 32); F4(25, h1, 36); F4(26, h1, 40); F4(27, h1, 44);
      F4(28, h1, 48); F4(29, h1, 52); F4(30, h1, 56); F4(31, h1, 60);
      F4(32, h2, 0);  F4(33, h2, 4);  F4(34, h2, 8);  F4(35, h2, 12);
      F4(36, h2, 16); F4(37, h2, 20);   // k=148..151: pad weights/h are 0
      g_s[col] = acc;
    }
    xcur = xn;
    __syncthreads();
    if (tid < Hn) {
      float gi = g_s[tid], gf = g_s[tid + 150], gg = g_s[tid + 300], go = g_s[tid + 450];
      float si = 1.f / (1.f + expf(-gi));
      float sf = 1.f / (1.f + expf(-gf));
      float so = 1.f / (1.f + expf(-go));
      c = sf * c + si * tanhf(gg);
      float h = so * tanhf(c);
      h_s[tid] = h;
      ho[(bT + rg) * Hn + tid] = h;
    }
    __syncthreads();
  }
  if (tid < Hn) { sH[b * Hn + tid] = h_s[tid]; sC[b * Hn + tid] = c; }
}

// ---------------- emissions: out = concat(hf,hb) @ Wl^T + bl (only t < len) ----------------
__global__ __launch_bounds__(256) void k_emis(
    const float* __restrict__ hf, const float* __restrict__ hb,
    const float* __restrict__ Wl, const float* __restrict__ bl,
    const int* __restrict__ lens, float* __restrict__ em) {
  int idx = blockIdx.x * 256 + threadIdx.x;
  int row = idx >> 5;
  int l = idx & 31;
  int b = row >> 9, t = row & 511;
  if (l >= Ln || t >= lens[b]) return;
  const float2* hf2 = (const float2*)(hf + (size_t)row * Hn);
  const float2* hb2 = (const float2*)(hb + (size_t)row * Hn);
  const float2* w0 = (const float2*)(Wl + (size_t)l * Dn);
  const float2* w1 = (const float2*)(Wl + (size_t)l * Dn + Hn);
  float acc = bl[l];
#pragma unroll 5
  for (int q = 0; q < 75; ++q) {
    float2 a = hf2[q], w = w0[q];
    acc = fmaf(a.x, w.x, fmaf(a.y, w.y, acc));
    float2 a2 = hb2[q], w2 = w1[q];
    acc = fmaf(a2.x, w2.x, fmaf(a2.y, w2.y, acc));
  }
  em[(size_t)row * Ln + l] = acc;
}

// ---------------- fused CRF: role 0 = denominator, 1 = viterbi, 2 = numerator ----------------
__global__ __launch_bounds__(64) void k_crf(
    const float* __restrict__ em, const int* __restrict__ labels, const int* __restrict__ lens,
    const float* __restrict__ trans, const float* __restrict__ st, const float* __restrict__ et,
    float* __restrict__ den, float* __restrict__ num, float* __restrict__ pathf) {
  const int role = blockIdx.x >> 7;
  const int b = blockIdx.x & 127;
  const int lane = threadIdx.x;
  const int len = lens[b];

  if (role == 2) {
    float s = 0.f;
    for (int t = lane; t < len; t += 64) {
      int lab = labels[b * Tn + t];
      s += em[((size_t)b * Tn + t) * Ln + lab];
      if (t + 1 < len) s += trans[lab * Ln + labels[b * Tn + t + 1]];
    }
#pragma unroll
    for (int off = 32; off; off >>= 1) s += __shfl_xor(s, off);
    if (lane == 0)
      num[b] = s + st[labels[b * Tn]] + et[labels[b * Tn + len - 1]];
    return;
  }

  __shared__ __align__(16) float em_s[Tn * Ln];     // 51.2 KB
  __shared__ unsigned char bp[Tn * Ln];             // 12.8 KB (vit role only)

  const float* ob = em + (size_t)b * Tn * Ln;
  {
    const float4* ob4 = (const float4*)ob;
    float4* es4 = (float4*)em_s;
    int n4 = (len * Ln + 3) >> 2;
    for (int u = lane; u < n4; u += 64) es4[u] = ob4[u];
  }
  const int cl = (lane < Ln) ? lane : 0;
  float col[Ln];
  if (role == 0) {
#pragma unroll
    for (int i = 0; i < Ln; ++i) col[i] = expf(trans[i * Ln + cl]);
  } else {
#pragma unroll
    for (int i = 0; i < Ln; ++i) col[i] = trans[i * Ln + cl];
  }
  __syncthreads();

  if (role == 0) {
    float alpha = (lane < Ln) ? st[lane] + em_s[lane] : -1e30f;
    for (int t = 1; t < len; ++t) {
      float m = alpha;
#pragma unroll
      for (int off = 32; off; off >>= 1) m = fmaxf(m, __shfl_xor(m, off));
      float p = (lane < Ln) ? expf(alpha - m) : 0.f;
      float ssum = 0.f;
#pragma unroll
      for (int i = 0; i < Ln; ++i) ssum = fmaf(__shfl(p, i), col[i], ssum);
      float e_t = em_s[t * Ln + cl];
      alpha = (lane < Ln) ? m + logf(ssum) + e_t : -1e30f;
    }
    float v = (lane < Ln) ? alpha + et[lane] : -1e30f;
    float m = v;
#pragma unroll
    for (int off = 32; off; off >>= 1) m = fmaxf(m, __shfl_xor(m, off));
    float ex = (lane < Ln) ? expf(v - m) : 0.f;
#pragma unroll
    for (int off = 32; off; off >>= 1) ex += __shfl_xor(ex, off);
    if (lane == 0) den[b] = m + logf(ex);
    return;
  }

  float delta = (lane < Ln) ? st[lane] + em_s[lane] : -1e30f;
  for (int t = 1; t < len; ++t) {
    float best = -1e30f; int bi = 0;
#pragma unroll
    for (int i = 0; i < Ln; ++i) {
      float v = __shfl(delta, i) + col[i];
      if (v > best) { best = v; bi = i; }
    }
    if (lane < Ln) bp[t * Ln + lane] = (unsigned char)bi;
    delta = (lane < Ln) ? best + em_s[t * Ln + cl] : -1e30f;
  }
  float v = (lane < Ln) ? delta + et[lane] : -1e30f;
  float m = v;
#pragma unroll
  for (int off = 32; off; off >>= 1) m = fmaxf(m, __shfl_xor(m, off));
  unsigned long long eq = __ballot(v == m);
  int last = __ffsll(eq) - 1;
  __syncthreads();
  if (lane == 0) {
    int cur = last;
    for (int t = len - 1; t >= 1; --t) {
      pathf[b * Tn + t] = (float)cur;
      cur = bp[t * Ln + cur];
    }
    pathf[b * Tn + 0] = (float)cur;
  }
  for (int t = len + lane; t < Tn; t += 64)
    pathf[b * Tn + t] = (float)last;
}

// ---------------- loss reduction ----------------
__global__ __launch_bounds__(64) void k_loss(const float* __restrict__ num, const float* __restrict__ den,
                                             float* __restrict__ out0) {
  int lane = threadIdx.x;
  float s = (num[lane] - den[lane]) + (num[lane + 64] - den[lane + 64]);
#pragma unroll
  for (int off = 32; off; off >>= 1) s += __shfl_xor(s, off);
  if (lane == 0) out0[0] = -s / (float)Bn;
}

extern "C" void kernel_launch(void* const* d_in, const int* in_sizes, int n_in,
                              void* d_out, int out_size, void* d_ws, size_t ws_size,
                              hipStream_t stream) {
  const float* X = (const float*)d_in[0];
  const float* mask = (const float*)d_in[1];
  const int* labels = (const int*)d_in[2];
  const float* Wihf = (const float*)d_in[3];
  const float* Whhf = (const float*)d_in[4];
  const float* bihf = (const float*)d_in[5];
  const float* bhhf = (const float*)d_in[6];
  const float* Wihb = (const float*)d_in[7];
  const float* Whhb = (const float*)d_in[8];
  const float* bihb = (const float*)d_in[9];
  const float* bhhb = (const float*)d_in[10];
  const float* Wl = (const float*)d_in[11];
  const float* bl = (const float*)d_in[12];
  const float* trans = (const float*)d_in[13];
  const float* st = (const float*)d_in[14];
  const float* et = (const float*)d_in[15];
  float* outv = (float*)d_out;

  auto planBytes = [](int CH) -> size_t {
    return ((size_t)2 * Bn * CH * Gn + 2 * (size_t)Bn * Tn * Hn + (size_t)Bn * Tn * Ln
            + 4 * (size_t)Bn * Hn + 3 * (size_t)Bn) * 4;
  };
  int CH, chSh;
  if      (ws_size >= planBytes(512)) { CH = 512; chSh = 9; }
  else if (ws_size >= planBytes(256)) { CH = 256; chSh = 8; }
  else if (ws_size >= planBytes(128)) { CH = 128; chSh = 7; }
  else                                { CH = 64;  chSh = 6; }
  const int tshift = chSh - 6;
  const int NC = Tn / CH;

  float* ws = (float*)d_ws;
  size_t off = 0;
  float* XgfC = ws + off; off += (size_t)Bn * CH * Gn;
  float* YbC  = ws + off; off += (size_t)Bn * CH * Gn;
  float* hf   = ws + off; off += (size_t)Bn * Tn * Hn;
  float* hb   = ws + off; off += (size_t)Bn * Tn * Hn;
  float* em   = ws + off; off += (size_t)Bn * Tn * Ln;
  float* sHf  = ws + off; off += (size_t)Bn * Hn;
  float* sCf  = ws + off; off += (size_t)Bn * Hn;
  float* sHb  = ws + off; off += (size_t)Bn * Hn;
  float* sCb  = ws + off; off += (size_t)Bn * Hn;
  float* num  = ws + off; off += Bn;
  float* den  = ws + off; off += Bn;
  int* lens   = (int*)(ws + off); off += Bn;

  k_len<<<Bn, 64, 0, stream>>>(mask, lens);

  for (int i = 0; i < NC; ++i) {
    int lo_f = i * CH;
    int lo_b = (NC - 1 - i) * CH;
    dim3 gg(Bn * (CH >> 6), 20);
    k_gemm_in<<<gg, 256, 0, stream>>>(X, Wihf, Wihb, bihf, bhhf, bihb, bhhb,
                                      lens, XgfC, YbC, lo_f, lo_b, tshift, chSh);
    k_lstm<<<2 * Bn, 640, 0, stream>>>(XgfC, YbC, Whhf, Whhb, lens, hf, hb,
                                       sHf, sCf, sHb, sCb, lo_f, lo_b, chSh, CH);
  }

  k_emis<<<(Bn * Tn * 32) / 256, 256, 0, stream>>>(hf, hb, Wl, bl, lens, em);

  k_crf<<<384, 64, 0, stream>>>(em, labels, lens, trans, st, et, den, num, outv + 1);
  k_loss<<<1, 64, 0, stream>>>(num, den, outv);
}